// Round 4
// baseline (14476.822 us; speedup 1.0000x reference)
//
#include <hip/hip_runtime.h>
#include <hip/hip_bf16.h>

// Dims: S=512, B=32, I=768, H=256, NH=8, HD=32, ML=512
#define SDIM 512
#define BDIM 32

__device__ __forceinline__ float b2f(ushort u) {
    union { uint32_t i; float f; } v; v.i = ((uint32_t)u) << 16; return v.f;
}
__device__ __forceinline__ ushort f2b(float f) {
    union { float f; uint32_t i; } v; v.f = f;
    uint32_t u = v.i;
    return (ushort)((u + 0x7fffu + ((u >> 16) & 1u)) >> 16);  // RNE
}
// packed bf16 pair (lo = even k, hi = odd k)
__device__ __forceinline__ float plo(uint32_t u) {
    union { uint32_t i; float f; } v; v.i = u << 16; return v.f;
}
__device__ __forceinline__ float phi(uint32_t u) {
    union { uint32_t i; float f; } v; v.i = u & 0xffff0000u; return v.f;
}

// ---------------------------------------------------------------------------
// Pack fp32 rows [R, 2Q] into bf16-pair uint32 [R, Q] (pairs along k):
//   out[r*Q+q] = bf16(in[r][2q+1])<<16 | bf16(in[r][2q])
// ---------------------------------------------------------------------------
__global__ __launch_bounds__(256) void pack_rows_kernel(
    const float* __restrict__ in, uint32_t* __restrict__ out, int total, int Q)
{
    const int idx = blockIdx.x * 256 + threadIdx.x;
    if (idx >= total) return;
    const int r = idx / Q, q = idx - r * Q;
    const float* rp = in + (size_t)r * (2 * Q) + 2 * q;
    out[idx] = ((uint32_t)f2b(rp[1]) << 16) | f2b(rp[0]);
}

// ---------------------------------------------------------------------------
// C[m,n] = sum_k A[m,k]*B[n,k] + bias[n] (+ relpos for K-proj).
// ABF16: A is bf16 (h_ner/h_re). ASWAP: A row [s*B+b] while m = b*S+s.
// ---------------------------------------------------------------------------
template<bool ABF16, bool ASWAP, bool RELPOS>
__global__ __launch_bounds__(256) void gemm_kernel(
    const void* __restrict__ Av, const float* __restrict__ Bw,
    const float* __restrict__ bias, const float* __restrict__ rp,
    float* __restrict__ C, int M, int N, int K)
{
    __shared__ float As[16][68];
    __shared__ float Bs[16][68];
    const int tid = threadIdx.x;
    const int tile_m = blockIdx.x * 64, tile_n = blockIdx.y * 64;
    const int lr = tid >> 2;            // 0..63: row within tile
    const int lk = (tid & 3) * 4;       // 0,4,8,12
    const int am = tile_m + lr;
    const int ar = ASWAP ? ((am & (SDIM - 1)) * BDIM + (am >> 9)) : am;
    const int bn = tile_n + lr;
    const int ty = tid >> 4, tx = tid & 15;
    float acc[4][4] = {};

    for (int k0 = 0; k0 < K; k0 += 16) {
        float f0, f1, f2, f3;
        if constexpr (ABF16) {
            ushort4 u = *(const ushort4*)((const ushort*)Av + (size_t)ar * K + k0 + lk);
            f0 = b2f(u.x); f1 = b2f(u.y); f2 = b2f(u.z); f3 = b2f(u.w);
        } else {
            float4 u = *(const float4*)((const float*)Av + (size_t)ar * K + k0 + lk);
            f0 = u.x; f1 = u.y; f2 = u.z; f3 = u.w;
        }
        As[lk + 0][lr] = f0; As[lk + 1][lr] = f1; As[lk + 2][lr] = f2; As[lk + 3][lr] = f3;
        float4 v = *(const float4*)(Bw + (size_t)bn * K + k0 + lk);
        Bs[lk + 0][lr] = v.x; Bs[lk + 1][lr] = v.y;
        Bs[lk + 2][lr] = v.z; Bs[lk + 3][lr] = v.w;
        __syncthreads();
        #pragma unroll
        for (int k = 0; k < 16; k++) {
            float4 a4 = *(const float4*)&As[k][ty * 4];
            float4 b4 = *(const float4*)&Bs[k][tx * 4];
            float av[4] = {a4.x, a4.y, a4.z, a4.w};
            float bv[4] = {b4.x, b4.y, b4.z, b4.w};
            #pragma unroll
            for (int j = 0; j < 4; j++)
                #pragma unroll
                for (int i = 0; i < 4; i++)
                    acc[j][i] += av[j] * bv[i];
        }
        __syncthreads();
    }
    #pragma unroll
    for (int j = 0; j < 4; j++) {
        const int gm = tile_m + ty * 4 + j;
        const int sgm = gm & (SDIM - 1);
        float4 o;
        float* op = &o.x;
        #pragma unroll
        for (int i = 0; i < 4; i++) {
            const int gn = tile_n + tx * 4 + i;
            float v = acc[j][i] + bias[gn];
            if (RELPOS) v += rp[((gn >> 5) << 14) + (sgm << 5) + (gn & 31)];
            op[i] = v;
        }
        *(float4*)(C + (size_t)gm * N + tile_n + tx * 4) = o;
    }
}

// ---------------------------------------------------------------------------
// Multi-CU weight-stationary PFN scan. 4 blocks per batch element (128 blocks
// total, all co-resident: 16 waves, ~110 VGPR, 16 KB LDS each). Each block
// holds a register-resident k-slice of Wh/Wt (packed bf16 pairs) and the two
// GEMVs exchange partial sums through L3 via agent-scope atomics guarded by
// generation-counter flags. No full grid barrier — only 4-block groups sync.
// ---------------------------------------------------------------------------
__global__ __launch_bounds__(1024, 4) void scan_kernel(
    const float* __restrict__ gx,       // [S,B,1280] precomputed x@Wi.T+bi
    const uint32_t* __restrict__ Whp,   // [1280,128] bf16 pairs along k
    const float* __restrict__ bh,       // [1280]
    const uint32_t* __restrict__ Wtp,   // [256,384] bf16 pairs along k
    const float* __restrict__ bt,       // [256]
    ushort* __restrict__ h_ner,         // [S,B,256] bf16
    ushort* __restrict__ h_re,          // [S,B,256] bf16
    float* __restrict__ Gpart,          // [32][4][1280]
    float* __restrict__ Cpart,          // [32][4][256]
    int* __restrict__ flags)            // [32][2][4], zeroed per launch
{
    const int blk = blockIdx.x;
    const int b = blk >> 2, p = blk & 3;
    const int tid = threadIdx.x;
    const int lane = tid & 63;
    const int ch = tid >> 8;            // cumsoftmax chunk 0..3
    const int wch = (tid >> 6) & 3;     // wave within chunk

    __shared__ float hs[256], cs[256], g[1280], cat[768], ps[1024];
    __shared__ float rmax[16], rsum[16];

    // --- preload register-resident weight slices (packed bf16 pairs) ---
    // wa: Wh row tid,            k in [p*64, p*64+64)           -> 32 pairs
    // wb: Wh row 1024+(tid>>2),  k in [p*64+(tid&3)*16, +16)    ->  8 pairs
    // wt: Wt row (tid&255),      k in [p*192+(tid>>8)*48, +48)  -> 24 pairs
    uint32_t wa[32], wb[8], wt[24];
    {
        const uint32_t* s1 = Whp + (size_t)tid * 128 + p * 32;
        #pragma unroll
        for (int i = 0; i < 32; i++) wa[i] = s1[i];
        const uint32_t* s2 = Whp + (size_t)(1024 + (tid >> 2)) * 128 + p * 32 + (tid & 3) * 8;
        #pragma unroll
        for (int i = 0; i < 8; i++) wb[i] = s2[i];
        const uint32_t* s3 = Wtp + (size_t)(tid & 255) * 384 + p * 96 + (tid >> 8) * 24;
        #pragma unroll
        for (int i = 0; i < 24; i++) wt[i] = s3[i];
    }
    if (tid < 256) { hs[tid] = 0.f; cs[tid] = 0.f; }
    __syncthreads();

    const size_t gb = (size_t)b * 4 * 1280;
    const size_t cbs = (size_t)b * 4 * 256;
    int* f1 = flags + b * 8;
    int* f2 = flags + b * 8 + 4;

    for (int t = 0; t < SDIM; t++) {
        const int gen = t + 1;
        const float* gxr = gx + (size_t)(t * BDIM + b) * 1280;
        // ---- phase 1: partial gates over this block's k-slice ----
        {
            const float* hp = hs + p * 64;
            float s1 = 0.f;
            #pragma unroll
            for (int i = 0; i < 32; i++)
                s1 += plo(wa[i]) * hp[2 * i] + phi(wa[i]) * hp[2 * i + 1];
            __hip_atomic_store(&Gpart[gb + (size_t)p * 1280 + tid], s1,
                               __ATOMIC_RELAXED, __HIP_MEMORY_SCOPE_AGENT);
            const float* hp2 = hs + p * 64 + (tid & 3) * 16;
            float s2 = 0.f;
            #pragma unroll
            for (int i = 0; i < 8; i++)
                s2 += plo(wb[i]) * hp2[2 * i] + phi(wb[i]) * hp2[2 * i + 1];
            ps[tid] = s2;   // 4 k-parts per extra row
        }
        __syncthreads();
        if (tid < 256) {
            const float se = ps[tid * 4] + ps[tid * 4 + 1] + ps[tid * 4 + 2] + ps[tid * 4 + 3];
            __hip_atomic_store(&Gpart[gb + (size_t)p * 1280 + 1024 + tid], se,
                               __ATOMIC_RELAXED, __HIP_MEMORY_SCOPE_AGENT);
        }
        __syncthreads();    // all Gpart stores drained (vmcnt(0) before barrier)
        if (tid == 0)
            __hip_atomic_store(&f1[p], gen, __ATOMIC_RELEASE, __HIP_MEMORY_SCOPE_AGENT);
        if (tid < 4)
            while (__hip_atomic_load(&f1[tid], __ATOMIC_ACQUIRE,
                                     __HIP_MEMORY_SCOPE_AGENT) < gen) {}
        __syncthreads();
        // ---- phase 2: reduce gates; tanh/cumsoftmax/combine (redundant) ----
        {
            float gv = gxr[tid] + bh[tid];
            #pragma unroll
            for (int q = 0; q < 4; q++)
                gv += __hip_atomic_load(&Gpart[gb + (size_t)q * 1280 + tid],
                                        __ATOMIC_RELAXED, __HIP_MEMORY_SCOPE_AGENT);
            g[tid] = gv;
        }
        __syncthreads();
        if (tid < 256) g[tid] = tanhf(g[tid]);
        float v;
        if (tid >= 768) {   // gate rows 1024..1279 (chunk 4)
            const int j2 = tid + 256;
            float gv = gxr[j2] + bh[j2];
            #pragma unroll
            for (int q = 0; q < 4; q++)
                gv += __hip_atomic_load(&Gpart[gb + (size_t)q * 1280 + j2],
                                        __ATOMIC_RELAXED, __HIP_MEMORY_SCOPE_AGENT);
            v = gv;
        } else {
            v = g[256 + tid];
        }
        float mx = v;
        #pragma unroll
        for (int off = 32; off >= 1; off >>= 1) mx = fmaxf(mx, __shfl_xor(mx, off, 64));
        if (lane == 0) rmax[ch * 4 + wch] = mx;
        __syncthreads();
        const float cmax = fmaxf(fmaxf(rmax[ch * 4], rmax[ch * 4 + 1]),
                                 fmaxf(rmax[ch * 4 + 2], rmax[ch * 4 + 3]));
        const float e = __expf(v - cmax);
        float wsum = e;
        #pragma unroll
        for (int off = 32; off >= 1; off >>= 1) wsum += __shfl_xor(wsum, off, 64);
        if (lane == 0) rsum[ch * 4 + wch] = wsum;
        float cum = e;   // inclusive wave scan
        #pragma unroll
        for (int off = 1; off <= 32; off <<= 1) {
            float tsh = __shfl_up(cum, (unsigned)off, 64);
            if (lane >= off) cum += tsh;
        }
        __syncthreads();
        const float tot = rsum[ch * 4] + rsum[ch * 4 + 1] + rsum[ch * 4 + 2] + rsum[ch * 4 + 3];
        float prev = 0.f;
        if (wch > 0) prev += rsum[ch * 4];
        if (wch > 1) prev += rsum[ch * 4 + 1];
        if (wch > 2) prev += rsum[ch * 4 + 2];
        float r = (cum + prev) / tot;
        if (ch == 0 || ch == 2) r = 1.f - r;   // eg_* = 1 - cumsoftmax
        g[256 + tid] = r;
        __syncthreads();
        // combine -> c_re, c_ner, share; emit this block's h-slice (bf16)
        if (tid < 256) {
            const float c = g[tid];
            const float egi = g[256 + tid], rgi = g[512 + tid];
            const float egc = g[768 + tid], rgc = g[1024 + tid];
            const float cin = cs[tid];
            const float ovc = rgc * egc, upc = rgc - ovc, dnc = egc - ovc;
            const float ovi = rgi * egi, upi = rgi - ovi, dni = egi - ovi;
            const float share = ovi * cin + ovc * c;
            const float cre = upi * cin + upc * c + share;
            const float cner = dni * cin + dnc * c + share;
            cat[tid] = cre; cat[256 + tid] = cner; cat[512 + tid] = share;
            if ((tid >> 5) == p) {    // blocks split the 256-wide h store 8*32... 4*64
            }
            if ((tid >> 6) == p) {
                const size_t ob = (size_t)(t * BDIM + b) * 256 + tid;
                h_re[ob] = f2b(tanhf(cre));
                h_ner[ob] = f2b(tanhf(cner));
            }
        }
        __syncthreads();
        // ---- phase 3: partial c_out over this block's cat k-slice ----
        {
            const int o = tid & 255, part = tid >> 8;
            const float* cp = cat + p * 192 + part * 48;
            float s = 0.f;
            #pragma unroll
            for (int i = 0; i < 24; i++)
                s += plo(wt[i]) * cp[2 * i] + phi(wt[i]) * cp[2 * i + 1];
            ps[part * 256 + o] = s;
        }
        __syncthreads();
        if (tid < 256) {
            const float cpv = ps[tid] + ps[256 + tid] + ps[512 + tid] + ps[768 + tid];
            __hip_atomic_store(&Cpart[cbs + (size_t)p * 256 + tid], cpv,
                               __ATOMIC_RELAXED, __HIP_MEMORY_SCOPE_AGENT);
        }
        __syncthreads();
        if (tid == 0)
            __hip_atomic_store(&f2[p], gen, __ATOMIC_RELEASE, __HIP_MEMORY_SCOPE_AGENT);
        if (tid < 4)
            while (__hip_atomic_load(&f2[tid], __ATOMIC_ACQUIRE,
                                     __HIP_MEMORY_SCOPE_AGENT) < gen) {}
        __syncthreads();
        if (tid < 256) {
            float co = bt[tid];
            #pragma unroll
            for (int q = 0; q < 4; q++)
                co += __hip_atomic_load(&Cpart[cbs + (size_t)q * 256 + tid],
                                        __ATOMIC_RELAXED, __HIP_MEMORY_SCOPE_AGENT);
            cs[tid] = co;
            hs[tid] = tanhf(co);
        }
        __syncthreads();
    }
}

// ---------------------------------------------------------------------------
// Attention for one (b, head): scores = q·(k+relpos) (relpos pre-folded into
// kk_ws), softmax, PV. Each thread owns one ki row of K in registers.
// ---------------------------------------------------------------------------
__global__ __launch_bounds__(512) void attn_kernel(
    const float* __restrict__ q_ws, const float* __restrict__ kk_ws,
    const float* __restrict__ v_ws, float* __restrict__ o_ws)
{
    __shared__ float sc[8 * 516];   // 8 q-rows x 512 probs, stride 516 (bank pad)
    __shared__ float ps[8 * 256];   // PV partials per wave
    __shared__ float sinv[8];
    const int bn = blockIdx.x;
    const int b = bn >> 3, n = bn & 7;
    const int tid = threadIdx.x;
    const int w = tid >> 6, lane = tid & 63;
    const int ki = w * 64 + lane;
    float kv[32];
    {
        const float4* kp = (const float4*)(kk_ws + (size_t)(b * 512 + ki) * 256 + n * 32);
        #pragma unroll
        for (int d4 = 0; d4 < 8; d4++) {
            float4 x = kp[d4];
            kv[4 * d4] = x.x; kv[4 * d4 + 1] = x.y; kv[4 * d4 + 2] = x.z; kv[4 * d4 + 3] = x.w;
        }
    }
    const int rr = lane >> 3, dq = lane & 7;

    for (int q0 = 0; q0 < 512; q0 += 8) {
        const float* qbase = q_ws + (size_t)(b * 512 + q0) * 256 + n * 32;
        #pragma unroll 1
        for (int r = 0; r < 8; r++) {
            const float* qr = qbase + r * 256;   // wave-uniform address
            float s = 0.f;
            #pragma unroll
            for (int d = 0; d < 32; d++) s += qr[d] * kv[d];
            sc[r * 516 + ki] = s;
        }
        __syncthreads();
        // softmax of row w by wave w
        {
            float* row = sc + w * 516;
            float4 a = ((const float4*)row)[lane];
            float4 c4 = ((const float4*)row)[lane + 64];
            float mx = fmaxf(fmaxf(fmaxf(a.x, a.y), fmaxf(a.z, a.w)),
                             fmaxf(fmaxf(c4.x, c4.y), fmaxf(c4.z, c4.w)));
            #pragma unroll
            for (int off = 32; off >= 1; off >>= 1) mx = fmaxf(mx, __shfl_xor(mx, off, 64));
            a.x = __expf(a.x - mx); a.y = __expf(a.y - mx);
            a.z = __expf(a.z - mx); a.w = __expf(a.w - mx);
            c4.x = __expf(c4.x - mx); c4.y = __expf(c4.y - mx);
            c4.z = __expf(c4.z - mx); c4.w = __expf(c4.w - mx);
            float sm = a.x + a.y + a.z + a.w + c4.x + c4.y + c4.z + c4.w;
            #pragma unroll
            for (int off = 32; off >= 1; off >>= 1) sm += __shfl_xor(sm, off, 64);
            ((float4*)row)[lane] = a;
            ((float4*)row)[lane + 64] = c4;
            if (lane == 0) sinv[w] = 1.f / sm;
        }
        __syncthreads();
        // PV: wave w covers ki in [w*64, w*64+64); lane -> (row rr, 4 dims dq*4)
        {
            float4 acc = {0.f, 0.f, 0.f, 0.f};
            const float* erow = sc + rr * 516 + w * 64;
            const float* vbase = v_ws + (size_t)(b * 512 + w * 64) * 256 + n * 32 + dq * 4;
            #pragma unroll 8
            for (int j = 0; j < 64; j++) {
                const float e = erow[j];
                float4 vv = *(const float4*)(vbase + (size_t)j * 256);
                acc.x += e * vv.x; acc.y += e * vv.y; acc.z += e * vv.z; acc.w += e * vv.w;
            }
            ((float4*)ps)[tid] = acc;
        }
        __syncthreads();
        if (tid < 256) {
            const int r2 = tid >> 5, d = tid & 31;
            float s = 0.f;
            #pragma unroll
            for (int ww = 0; ww < 8; ww++) s += ps[ww * 256 + r2 * 32 + d];
            o_ws[(size_t)(b * 512 + q0 + r2) * 256 + n * 32 + d] = s * sinv[r2];
        }
        __syncthreads();
    }
}

// ---------------------------------------------------------------------------
// y = LN(hb + proj) -> fp32 output in [S,B,H] order (residual hb is bf16)
// ---------------------------------------------------------------------------
__global__ __launch_bounds__(256) void ln_kernel(
    const float* __restrict__ proj, const ushort* __restrict__ hsrc,
    const float* __restrict__ lng, const float* __restrict__ lnb,
    float* __restrict__ outp)
{
    const int m = blockIdx.x;           // b*512 + s
    const int j = threadIdx.x;
    const int b = m >> 9, s = m & 511;
    const size_t oidx = (size_t)(s * 32 + b) * 256 + j;
    const float y = proj[(size_t)m * 256 + j] + b2f(hsrc[oidx]);
    float sum = y, sq = y * y;
    #pragma unroll
    for (int off = 32; off >= 1; off >>= 1) {
        sum += __shfl_xor(sum, off, 64);
        sq += __shfl_xor(sq, off, 64);
    }
    __shared__ float r1[4], r2[4];
    const int wv = j >> 6;
    if ((j & 63) == 0) { r1[wv] = sum; r2[wv] = sq; }
    __syncthreads();
    const float ts = r1[0] + r1[1] + r1[2] + r1[3];
    const float tq = r2[0] + r2[1] + r2[2] + r2[3];
    const float mean = ts * (1.f / 256.f);
    const float var = tq * (1.f / 256.f) - mean * mean;
    const float o = (y - mean) * rsqrtf(var + 1e-5f) * lng[j] + lnb[j];
    outp[oidx] = o;
}

extern "C" void kernel_launch(void* const* d_in, const int* in_sizes, int n_in,
                              void* d_out, int out_size, void* d_ws, size_t ws_size,
                              hipStream_t stream) {
    (void)in_sizes; (void)n_in; (void)out_size; (void)ws_size;
    const float* x   = (const float*)d_in[0];
    const float* Wi  = (const float*)d_in[1];
    const float* bi  = (const float*)d_in[2];
    const float* Wh  = (const float*)d_in[3];
    const float* bh  = (const float*)d_in[4];
    const float* Wt  = (const float*)d_in[5];
    const float* bt  = (const float*)d_in[6];
    const float* Wq  = (const float*)d_in[7];
    const float* bq  = (const float*)d_in[8];
    const float* Wk  = (const float*)d_in[9];
    const float* bk  = (const float*)d_in[10];
    const float* Wv  = (const float*)d_in[11];
    const float* bv  = (const float*)d_in[12];
    const float* Wo  = (const float*)d_in[13];
    const float* bo  = (const float*)d_in[14];
    const float* rp  = (const float*)d_in[15];
    const float* lng = (const float*)d_in[16];
    const float* lnb = (const float*)d_in[17];
    float* outp = (float*)d_out;

    float* ws = (float*)d_ws;
    // pool [0, 20971520): gx fp32 [16384,1280] during scan; attn scratch after
    float* gx    = ws;
    float* q_ws  = ws;
    float* kk_ws = ws + 4194304;
    float* v_ws  = ws + 8388608;
    float* o_ws  = ws + 12582912;
    float* pj_ws = ws + 16777216;                  // ends exactly at 20971520
    ushort* hner16 = (ushort*)(ws + 20971520);     // [S,B,256] bf16
    ushort* hre16  = (ushort*)(ws + 23068672);
    uint32_t* Whp  = (uint32_t*)(ws + 25165824);   // [1280,128] bf16 pairs
    uint32_t* Wtp  = (uint32_t*)(ws + 25329664);   // [256,384] bf16 pairs
    float* Gpart   = ws + 25427968;                // [32][4][1280]
    float* Cpart   = ws + 25591808;                // [32][4][256]
    int*   flags   = (int*)(ws + 25624576);        // [32][2][4]
    // total: 25624640 floats = 102.5 MB

    // 0) pack recurrent weights (bf16 pairs along k, original row order)
    pack_rows_kernel<<<dim3(640), 256, 0, stream>>>(Wh, Whp, 1280 * 128, 128);
    pack_rows_kernel<<<dim3(384), 256, 0, stream>>>(Wt, Wtp, 256 * 384, 384);
    hipMemsetAsync(flags, 0, 256 * sizeof(int), stream);

    // 1) gates_x = x @ Wi.T + bi   [16384,1280]
    gemm_kernel<false, false, false><<<dim3(256, 20), 256, 0, stream>>>(
        x, Wi, bi, nullptr, gx, 16384, 1280, 768);

    // 2) multi-CU sequential scan (4 blocks per batch element)
    scan_kernel<<<dim3(128), dim3(1024), 0, stream>>>(
        gx, Whp, bh, Wtp, bt, hner16, hre16, Gpart, Cpart, flags);

    // 3) three attentions: (h_ner,0), (h_re,1), (h_re,2)
    for (int i = 0; i < 3; i++) {
        const ushort* src16 = (i == 0) ? hner16 : hre16;
        gemm_kernel<true, true, false><<<dim3(256, 4), 256, 0, stream>>>(
            src16, Wq + (size_t)i * 65536, bq + i * 256, nullptr, q_ws, 16384, 256, 256);
        gemm_kernel<true, true, true><<<dim3(256, 4), 256, 0, stream>>>(
            src16, Wk + (size_t)i * 65536, bk + i * 256, rp + (size_t)i * 131072, kk_ws, 16384, 256, 256);
        gemm_kernel<true, true, false><<<dim3(256, 4), 256, 0, stream>>>(
            src16, Wv + (size_t)i * 65536, bv + i * 256, nullptr, v_ws, 16384, 256, 256);
        attn_kernel<<<dim3(256), dim3(512), 0, stream>>>(q_ws, kk_ws, v_ws, o_ws);
        gemm_kernel<false, false, false><<<dim3(256, 4), 256, 0, stream>>>(
            o_ws, Wo + (size_t)i * 65536, bo + i * 256, nullptr, pj_ws, 16384, 256, 256);
        ln_kernel<<<dim3(16384), dim3(256), 0, stream>>>(
            pj_ws, src16, lng, lnb, outp + (size_t)i * 4194304);
    }
}

// Round 5
// 8278.556 us; speedup vs baseline: 1.7487x; 1.7487x over previous
//
#include <hip/hip_runtime.h>
#include <hip/hip_bf16.h>

// Dims: S=512, B=32, I=768, H=256, NH=8, HD=32, ML=512
#define SDIM 512
#define BDIM 32

typedef _Float16 v2h __attribute__((ext_vector_type(2)));

__device__ __forceinline__ float b2f(ushort u) {
    union { uint32_t i; float f; } v; v.i = ((uint32_t)u) << 16; return v.f;
}
__device__ __forceinline__ ushort f2b(float f) {
    union { float f; uint32_t i; } v; v.f = f;
    uint32_t u = v.i;
    return (ushort)((u + 0x7fffu + ((u >> 16) & 1u)) >> 16);  // RNE
}
__device__ __forceinline__ ushort f2h(float f) {
    union { _Float16 h; ushort u; } v; v.h = (_Float16)f; return v.u;
}
// 2 MACs in one VALU op: acc += w.lo*h.lo + w.hi*h.hi (fp32 accumulate)
__device__ __forceinline__ float dot2(uint32_t w, uint32_t h, float acc) {
#if __has_builtin(__builtin_amdgcn_fdot2)
    union { uint32_t u; v2h v; } a, b;
    a.u = w; b.u = h;
    return __builtin_amdgcn_fdot2(a.v, b.v, acc, false);
#else
    union { uint32_t u; v2h v; } a, b;
    a.u = w; b.u = h;
    return acc + (float)a.v.x * (float)b.v.x + (float)a.v.y * (float)b.v.y;
#endif
}
// fast tanh: 1 - 2/(exp(2x)+1); exact at +/-inf, ~1e-7 rel via v_exp/v_rcp
__device__ __forceinline__ float ftanh(float x) {
    const float t = __expf(2.f * x);
    return 1.f - 2.f * __builtin_amdgcn_rcpf(t + 1.f);
}

// 8 f16-pairs (16 k) of weights (k-major, stride) against packed h from LDS
#define DCHUNK8(WP, STRIDE, HQ, ACC)                                           \
    {                                                                          \
        uint4 hA = *(const uint4*)((HQ) + 0);                                  \
        uint4 hB = *(const uint4*)((HQ) + 4);                                  \
        ACC = dot2((WP)[(size_t)(0) * (STRIDE)], hA.x, ACC);                   \
        ACC = dot2((WP)[(size_t)(1) * (STRIDE)], hA.y, ACC);                   \
        ACC = dot2((WP)[(size_t)(2) * (STRIDE)], hA.z, ACC);                   \
        ACC = dot2((WP)[(size_t)(3) * (STRIDE)], hA.w, ACC);                   \
        ACC = dot2((WP)[(size_t)(4) * (STRIDE)], hB.x, ACC);                   \
        ACC = dot2((WP)[(size_t)(5) * (STRIDE)], hB.y, ACC);                   \
        ACC = dot2((WP)[(size_t)(6) * (STRIDE)], hB.z, ACC);                   \
        ACC = dot2((WP)[(size_t)(7) * (STRIDE)], hB.w, ACC);                   \
    }

// ---------------------------------------------------------------------------
// [R,C] -> [C,R] fp32 transpose (LDS tiled). Grid: (C/32, R/32), 256 threads.
// ---------------------------------------------------------------------------
__global__ __launch_bounds__(256) void transpose_kernel(
    const float* __restrict__ src, float* __restrict__ dst, int R, int C)
{
    __shared__ float t[32][33];
    const int bx = blockIdx.x * 32, by = blockIdx.y * 32;
    const int x = threadIdx.x & 31, y = threadIdx.x >> 5;   // y: 0..7
    #pragma unroll
    for (int dy = 0; dy < 32; dy += 8)
        t[y + dy][x] = src[(size_t)(by + y + dy) * C + bx + x];
    __syncthreads();
    #pragma unroll
    for (int dy = 0; dy < 32; dy += 8)
        dst[(size_t)(bx + y + dy) * R + by + x] = t[x][y + dy];
}

// ---------------------------------------------------------------------------
// Pack k-major fp32 [2P, J] into f16-pair uint32 [P, J]:
//   out[p*J + j] = f16(in[(2p+1)*J + j]) << 16 | f16(in[2p*J + j])
// ---------------------------------------------------------------------------
__global__ __launch_bounds__(256) void pack_kernel(
    const float* __restrict__ in, uint32_t* __restrict__ out, int P, int J)
{
    const int idx = blockIdx.x * 256 + threadIdx.x;
    if (idx >= P * J) return;
    const int p = idx / J, j = idx - p * J;
    const ushort lo = f2h(in[(size_t)(2 * p) * J + j]);
    const ushort hi = f2h(in[(size_t)(2 * p + 1) * J + j]);
    out[idx] = ((uint32_t)hi << 16) | lo;
}

// ---------------------------------------------------------------------------
// C[m,n] = sum_k A[m,k]*B[n,k] + bias[n] (+ relpos for K-proj).
// ABF16: A is bf16 (h_ner/h_re). ASWAP: A row [s*B+b] while m = b*S+s.
// ---------------------------------------------------------------------------
template<bool ABF16, bool ASWAP, bool RELPOS>
__global__ __launch_bounds__(256) void gemm_kernel(
    const void* __restrict__ Av, const float* __restrict__ Bw,
    const float* __restrict__ bias, const float* __restrict__ rp,
    float* __restrict__ C, int M, int N, int K)
{
    __shared__ float As[16][68];
    __shared__ float Bs[16][68];
    const int tid = threadIdx.x;
    const int tile_m = blockIdx.x * 64, tile_n = blockIdx.y * 64;
    const int lr = tid >> 2;            // 0..63: row within tile
    const int lk = (tid & 3) * 4;       // 0,4,8,12
    const int am = tile_m + lr;
    const int ar = ASWAP ? ((am & (SDIM - 1)) * BDIM + (am >> 9)) : am;
    const int bn = tile_n + lr;
    const int ty = tid >> 4, tx = tid & 15;
    float acc[4][4] = {};

    for (int k0 = 0; k0 < K; k0 += 16) {
        float f0, f1, f2, f3;
        if constexpr (ABF16) {
            ushort4 u = *(const ushort4*)((const ushort*)Av + (size_t)ar * K + k0 + lk);
            f0 = b2f(u.x); f1 = b2f(u.y); f2 = b2f(u.z); f3 = b2f(u.w);
        } else {
            float4 u = *(const float4*)((const float*)Av + (size_t)ar * K + k0 + lk);
            f0 = u.x; f1 = u.y; f2 = u.z; f3 = u.w;
        }
        As[lk + 0][lr] = f0; As[lk + 1][lr] = f1; As[lk + 2][lr] = f2; As[lk + 3][lr] = f3;
        float4 v = *(const float4*)(Bw + (size_t)bn * K + k0 + lk);
        Bs[lk + 0][lr] = v.x; Bs[lk + 1][lr] = v.y;
        Bs[lk + 2][lr] = v.z; Bs[lk + 3][lr] = v.w;
        __syncthreads();
        #pragma unroll
        for (int k = 0; k < 16; k++) {
            float4 a4 = *(const float4*)&As[k][ty * 4];
            float4 b4 = *(const float4*)&Bs[k][tx * 4];
            float av[4] = {a4.x, a4.y, a4.z, a4.w};
            float bv[4] = {b4.x, b4.y, b4.z, b4.w};
            #pragma unroll
            for (int j = 0; j < 4; j++)
                #pragma unroll
                for (int i = 0; i < 4; i++)
                    acc[j][i] += av[j] * bv[i];
        }
        __syncthreads();
    }
    #pragma unroll
    for (int j = 0; j < 4; j++) {
        const int gm = tile_m + ty * 4 + j;
        const int sgm = gm & (SDIM - 1);
        float4 o;
        float* op = &o.x;
        #pragma unroll
        for (int i = 0; i < 4; i++) {
            const int gn = tile_n + tx * 4 + i;
            float v = acc[j][i] + bias[gn];
            if (RELPOS) v += rp[((gn >> 5) << 14) + (sgm << 5) + (gn & 31)];
            op[i] = v;
        }
        *(float4*)(C + (size_t)gm * N + tile_n + tx * 4) = o;
    }
}

// ---------------------------------------------------------------------------
// Sequential PFN scan. One workgroup (1024 thr) per batch element.
// Weights f16-pair packed, k-major: Wh2 [128][1280], Wt2 [384][256].
// GEMVs use v_dot2_f32_f16 (2 MACs/op, fp32 accum); h/cat packed f16 in LDS.
// ---------------------------------------------------------------------------
__global__ __launch_bounds__(1024) void scan_kernel(
    const float* __restrict__ gx,       // [S,B,1280] precomputed x@Wi.T+bi
    const uint32_t* __restrict__ Wh2,   // [128,1280] f16 pairs over k
    const float* __restrict__ bh,       // [1280]
    const uint32_t* __restrict__ Wt2,   // [384,256] f16 pairs over k
    const float* __restrict__ bt,       // [256]
    ushort* __restrict__ h_ner,         // [S,B,256] bf16
    ushort* __restrict__ h_re)          // [S,B,256] bf16
{
    const int b = blockIdx.x;
    const int tid = threadIdx.x;
    __shared__ float cs[256], g[1280], ext[1024];
    __shared__ uint32_t hs_pk[128], cat_pk[384];
    __shared__ float rmax[16], rsum[16];
    if (tid < 256) cs[tid] = 0.f;
    if (tid < 128) hs_pk[tid] = 0u;
    __syncthreads();
    const int lane = tid & 63;
    const int ch = tid >> 8;            // cumsoftmax chunk 0..3
    const int wch = (tid >> 6) & 3;     // wave within chunk
    const int er = tid & 255;           // extra-row id / GEMV2 output id
    const int ep = tid >> 8;            // k-part 0..3

    for (int t = 0; t < SDIM; t++) {
        const float* gxr = gx + (size_t)(t * BDIM + b) * 1280;
        // ---- gates = gx + bh + h @ Wh.T ----
        // main: rows 0..1023 (row j = tid, full k = 128 pairs)
        {
            float a1 = 0.f;
            const uint32_t* wc = Wh2 + tid;
            #pragma unroll 2
            for (int q = 0; q < 128; q += 8)
                DCHUNK8(wc + (size_t)q * 1280, 1280, hs_pk + q, a1);
            g[tid] = gxr[tid] + bh[tid] + a1;
        }
        // extra: rows 1024..1279, k split 4 ways (32 pairs per part)
        {
            float ae = 0.f;
            const uint32_t* wc = Wh2 + 1024 + er;
            const int qb = ep * 32;
            #pragma unroll 2
            for (int i = 0; i < 32; i += 8)
                DCHUNK8(wc + (size_t)(qb + i) * 1280, 1280, hs_pk + qb + i, ae);
            ext[ep * 256 + er] = ae;
        }
        __syncthreads();
        // ---- c = tanh(chunk0); cumsoftmax on chunks 1..4 (in place) ----
        if (tid < 256) g[tid] = ftanh(g[tid]);
        float v;
        if (tid >= 768) {   // gate rows 1024..1279: finish 4-part reduction
            const int r = tid - 768;
            v = gxr[1024 + r] + bh[1024 + r]
              + ext[r] + ext[256 + r] + ext[512 + r] + ext[768 + r];
        } else {
            v = g[256 + tid];
        }
        float mx = v;
        #pragma unroll
        for (int off = 32; off >= 1; off >>= 1) mx = fmaxf(mx, __shfl_xor(mx, off, 64));
        if (lane == 0) rmax[ch * 4 + wch] = mx;
        __syncthreads();
        const float cmax = fmaxf(fmaxf(rmax[ch * 4], rmax[ch * 4 + 1]),
                                 fmaxf(rmax[ch * 4 + 2], rmax[ch * 4 + 3]));
        const float e = __expf(v - cmax);
        float wsum = e;
        #pragma unroll
        for (int off = 32; off >= 1; off >>= 1) wsum += __shfl_xor(wsum, off, 64);
        if (lane == 0) rsum[ch * 4 + wch] = wsum;
        float cum = e;   // inclusive wave scan
        #pragma unroll
        for (int off = 1; off <= 32; off <<= 1) {
            float tsh = __shfl_up(cum, (unsigned)off, 64);
            if (lane >= off) cum += tsh;
        }
        __syncthreads();
        const float tot = rsum[ch * 4] + rsum[ch * 4 + 1] + rsum[ch * 4 + 2] + rsum[ch * 4 + 3];
        float prev = 0.f;
        if (wch > 0) prev += rsum[ch * 4];
        if (wch > 1) prev += rsum[ch * 4 + 1];
        if (wch > 2) prev += rsum[ch * 4 + 2];
        float r = (cum + prev) * __builtin_amdgcn_rcpf(tot);
        if (ch == 0 || ch == 2) r = 1.f - r;   // eg_* = 1 - cumsoftmax
        g[256 + tid] = r;
        __syncthreads();
        // ---- combine gates -> c_re, c_ner, share; emit h_ner/h_re (bf16) ----
        if (tid < 256) {
            const float c = g[tid];
            const float egi = g[256 + tid], rgi = g[512 + tid];
            const float egc = g[768 + tid], rgc = g[1024 + tid];
            const float cin = cs[tid];
            const float ovc = rgc * egc, upc = rgc - ovc, dnc = egc - ovc;
            const float ovi = rgi * egi, upi = rgi - ovi, dni = egi - ovi;
            const float share = ovi * cin + ovc * c;
            const float cre = upi * cin + upc * c + share;
            const float cner = dni * cin + dnc * c + share;
            ((_Float16*)cat_pk)[tid]       = (_Float16)cre;
            ((_Float16*)cat_pk)[256 + tid] = (_Float16)cner;
            ((_Float16*)cat_pk)[512 + tid] = (_Float16)share;
            const size_t ob = (size_t)(t * BDIM + b) * 256 + tid;
            h_re[ob] = f2b(ftanh(cre));
            h_ner[ob] = f2b(ftanh(cner));
        }
        __syncthreads();
        // ---- c_out = cat @ Wt.T + bt (4 k-partials of 96 pairs per output) ----
        {
            float s = 0.f;
            const uint32_t* wc = Wt2 + er;
            const int qb = ep * 96;
            #pragma unroll 2
            for (int i = 0; i < 96; i += 8)
                DCHUNK8(wc + (size_t)(qb + i) * 256, 256, cat_pk + qb + i, s);
            g[ep * 256 + er] = s;
        }
        __syncthreads();
        if (tid < 256) {
            const float co = g[tid] + g[256 + tid] + g[512 + tid] + g[768 + tid] + bt[tid];
            cs[tid] = co;
            ((_Float16*)hs_pk)[tid] = (_Float16)ftanh(co);
        }
        __syncthreads();
    }
}

// ---------------------------------------------------------------------------
// Attention for one (b, head): scores = q·(k+relpos) (relpos pre-folded into
// kk_ws), softmax, PV. Each thread owns one ki row of K in registers.
// ---------------------------------------------------------------------------
__global__ __launch_bounds__(512) void attn_kernel(
    const float* __restrict__ q_ws, const float* __restrict__ kk_ws,
    const float* __restrict__ v_ws, float* __restrict__ o_ws)
{
    __shared__ float sc[8 * 516];   // 8 q-rows x 512 probs, stride 516 (bank pad)
    __shared__ float ps[8 * 256];   // PV partials per wave
    __shared__ float sinv[8];
    const int bn = blockIdx.x;
    const int b = bn >> 3, n = bn & 7;
    const int tid = threadIdx.x;
    const int w = tid >> 6, lane = tid & 63;
    const int ki = w * 64 + lane;
    float kv[32];
    {
        const float4* kp = (const float4*)(kk_ws + (size_t)(b * 512 + ki) * 256 + n * 32);
        #pragma unroll
        for (int d4 = 0; d4 < 8; d4++) {
            float4 x = kp[d4];
            kv[4 * d4] = x.x; kv[4 * d4 + 1] = x.y; kv[4 * d4 + 2] = x.z; kv[4 * d4 + 3] = x.w;
        }
    }
    const int rr = lane >> 3, dq = lane & 7;

    for (int q0 = 0; q0 < 512; q0 += 8) {
        const float* qbase = q_ws + (size_t)(b * 512 + q0) * 256 + n * 32;
        #pragma unroll 1
        for (int r = 0; r < 8; r++) {
            const float* qr = qbase + r * 256;   // wave-uniform address
            float s = 0.f;
            #pragma unroll
            for (int d = 0; d < 32; d++) s += qr[d] * kv[d];
            sc[r * 516 + ki] = s;
        }
        __syncthreads();
        // softmax of row w by wave w
        {
            float* row = sc + w * 516;
            float4 a = ((const float4*)row)[lane];
            float4 c4 = ((const float4*)row)[lane + 64];
            float mx = fmaxf(fmaxf(fmaxf(a.x, a.y), fmaxf(a.z, a.w)),
                             fmaxf(fmaxf(c4.x, c4.y), fmaxf(c4.z, c4.w)));
            #pragma unroll
            for (int off = 32; off >= 1; off >>= 1) mx = fmaxf(mx, __shfl_xor(mx, off, 64));
            a.x = __expf(a.x - mx); a.y = __expf(a.y - mx);
            a.z = __expf(a.z - mx); a.w = __expf(a.w - mx);
            c4.x = __expf(c4.x - mx); c4.y = __expf(c4.y - mx);
            c4.z = __expf(c4.z - mx); c4.w = __expf(c4.w - mx);
            float sm = a.x + a.y + a.z + a.w + c4.x + c4.y + c4.z + c4.w;
            #pragma unroll
            for (int off = 32; off >= 1; off >>= 1) sm += __shfl_xor(sm, off, 64);
            ((float4*)row)[lane] = a;
            ((float4*)row)[lane + 64] = c4;
            if (lane == 0) sinv[w] = 1.f / sm;
        }
        __syncthreads();
        // PV: wave w covers ki in [w*64, w*64+64); lane -> (row rr, 4 dims dq*4)
        {
            float4 acc = {0.f, 0.f, 0.f, 0.f};
            const float* erow = sc + rr * 516 + w * 64;
            const float* vbase = v_ws + (size_t)(b * 512 + w * 64) * 256 + n * 32 + dq * 4;
            #pragma unroll 8
            for (int j = 0; j < 64; j++) {
                const float e = erow[j];
                float4 vv = *(const float4*)(vbase + (size_t)j * 256);
                acc.x += e * vv.x; acc.y += e * vv.y; acc.z += e * vv.z; acc.w += e * vv.w;
            }
            ((float4*)ps)[tid] = acc;
        }
        __syncthreads();
        if (tid < 256) {
            const int r2 = tid >> 5, d = tid & 31;
            float s = 0.f;
            #pragma unroll
            for (int ww = 0; ww < 8; ww++) s += ps[ww * 256 + r2 * 32 + d];
            o_ws[(size_t)(b * 512 + q0 + r2) * 256 + n * 32 + d] = s * sinv[r2];
        }
        __syncthreads();
    }
}

// ---------------------------------------------------------------------------
// y = LN(hb + proj) -> fp32 output in [S,B,H] order (residual hb is bf16)
// ---------------------------------------------------------------------------
__global__ __launch_bounds__(256) void ln_kernel(
    const float* __restrict__ proj, const ushort* __restrict__ hsrc,
    const float* __restrict__ lng, const float* __restrict__ lnb,
    float* __restrict__ outp)
{
    const int m = blockIdx.x;           // b*512 + s
    const int j = threadIdx.x;
    const int b = m >> 9, s = m & 511;
    const size_t oidx = (size_t)(s * 32 + b) * 256 + j;
    const float y = proj[(size_t)m * 256 + j] + b2f(hsrc[oidx]);
    float sum = y, sq = y * y;
    #pragma unroll
    for (int off = 32; off >= 1; off >>= 1) {
        sum += __shfl_xor(sum, off, 64);
        sq += __shfl_xor(sq, off, 64);
    }
    __shared__ float r1[4], r2[4];
    const int wv = j >> 6;
    if ((j & 63) == 0) { r1[wv] = sum; r2[wv] = sq; }
    __syncthreads();
    const float ts = r1[0] + r1[1] + r1[2] + r1[3];
    const float tq = r2[0] + r2[1] + r2[2] + r2[3];
    const float mean = ts * (1.f / 256.f);
    const float var = tq * (1.f / 256.f) - mean * mean;
    const float o = (y - mean) * rsqrtf(var + 1e-5f) * lng[j] + lnb[j];
    outp[oidx] = o;
}

extern "C" void kernel_launch(void* const* d_in, const int* in_sizes, int n_in,
                              void* d_out, int out_size, void* d_ws, size_t ws_size,
                              hipStream_t stream) {
    (void)in_sizes; (void)n_in; (void)out_size; (void)ws_size;
    const float* x   = (const float*)d_in[0];
    const float* Wi  = (const float*)d_in[1];
    const float* bi  = (const float*)d_in[2];
    const float* Wh  = (const float*)d_in[3];
    const float* bh  = (const float*)d_in[4];
    const float* Wt  = (const float*)d_in[5];
    const float* bt  = (const float*)d_in[6];
    const float* Wq  = (const float*)d_in[7];
    const float* bq  = (const float*)d_in[8];
    const float* Wk  = (const float*)d_in[9];
    const float* bk  = (const float*)d_in[10];
    const float* Wv  = (const float*)d_in[11];
    const float* bv  = (const float*)d_in[12];
    const float* Wo  = (const float*)d_in[13];
    const float* bo  = (const float*)d_in[14];
    const float* rp  = (const float*)d_in[15];
    const float* lng = (const float*)d_in[16];
    const float* lnb = (const float*)d_in[17];
    float* outp = (float*)d_out;

    float* ws = (float*)d_ws;
    // pool [0, 20971520): gx fp32 [16384,1280] during scan; attn scratch after
    float* gx    = ws;
    float* q_ws  = ws;
    float* kk_ws = ws + 4194304;
    float* v_ws  = ws + 8388608;
    float* o_ws  = ws + 12582912;
    float* pj_ws = ws + 16777216;            // ends exactly at 20971520
    ushort* hner16 = (ushort*)(ws + 20971520);   // [S,B,256] bf16
    ushort* hre16  = (ushort*)(ws + 23068672);
    float* WhT = ws + 25165824;              // [256,1280] fp32
    float* WtT = ws + 25493504;              // [768,256] fp32
    uint32_t* Wh2 = (uint32_t*)(ws + 25690112);  // [128,1280] f16 pairs
    uint32_t* Wt2 = (uint32_t*)(ws + 25853952);  // [384,256] f16 pairs
    // total: 25952256 floats = 103.8 MB

    // 0) transpose recurrent weights to k-major, then pack to f16 pairs
    transpose_kernel<<<dim3(8, 40), 256, 0, stream>>>(Wh, WhT, 1280, 256);
    transpose_kernel<<<dim3(24, 8), 256, 0, stream>>>(Wt, WtT, 256, 768);
    pack_kernel<<<dim3(640), 256, 0, stream>>>(WhT, Wh2, 128, 1280);
    pack_kernel<<<dim3(384), 256, 0, stream>>>(WtT, Wt2, 384, 256);

    // 1) gates_x = x @ Wi.T + bi   [16384,1280]
    gemm_kernel<false, false, false><<<dim3(256, 20), 256, 0, stream>>>(
        x, Wi, bi, nullptr, gx, 16384, 1280, 768);

    // 2) sequential scan (one block per batch element)
    scan_kernel<<<dim3(32), dim3(1024), 0, stream>>>(gx, Wh2, bh, Wt2, bt, hner16, hre16);

    // 3) three attentions: (h_ner,0), (h_re,1), (h_re,2)
    for (int i = 0; i < 3; i++) {
        const ushort* src16 = (i == 0) ? hner16 : hre16;
        gemm_kernel<true, true, false><<<dim3(256, 4), 256, 0, stream>>>(
            src16, Wq + (size_t)i * 65536, bq + i * 256, nullptr, q_ws, 16384, 256, 256);
        gemm_kernel<true, true, true><<<dim3(256, 4), 256, 0, stream>>>(
            src16, Wk + (size_t)i * 65536, bk + i * 256, rp + (size_t)i * 131072, kk_ws, 16384, 256, 256);
        gemm_kernel<true, true, false><<<dim3(256, 4), 256, 0, stream>>>(
            src16, Wv + (size_t)i * 65536, bv + i * 256, nullptr, v_ws, 16384, 256, 256);
        attn_kernel<<<dim3(256), dim3(512), 0, stream>>>(q_ws, kk_ws, v_ws, o_ws);
        gemm_kernel<false, false, false><<<dim3(256, 4), 256, 0, stream>>>(
            o_ws, Wo + (size_t)i * 65536, bo + i * 256, nullptr, pj_ws, 16384, 256, 256);
        ln_kernel<<<dim3(16384), dim3(256), 0, stream>>>(
            pj_ws, src16, lng, lnb, outp + (size_t)i * 4194304);
    }
}

// Round 7
// 7437.820 us; speedup vs baseline: 1.9464x; 1.1130x over previous
//
#include <hip/hip_runtime.h>
#include <hip/hip_bf16.h>

// Dims: S=512, B=32, I=768, H=256, NH=8, HD=32, ML=512
#define SDIM 512
#define BDIM 32

typedef _Float16 v2h __attribute__((ext_vector_type(2)));
typedef short bf16x8 __attribute__((ext_vector_type(8)));
typedef float f32x4 __attribute__((ext_vector_type(4)));

__device__ __forceinline__ float b2f(ushort u) {
    union { uint32_t i; float f; } v; v.i = ((uint32_t)u) << 16; return v.f;
}
__device__ __forceinline__ ushort f2b(float f) {
    union { float f; uint32_t i; } v; v.f = f;
    uint32_t u = v.i;
    return (ushort)((u + 0x7fffu + ((u >> 16) & 1u)) >> 16);  // RNE
}
__device__ __forceinline__ ushort f2h(float f) {
    union { _Float16 h; ushort u; } v; v.h = (_Float16)f; return v.u;
}
// 2 f16 MACs in one VALU op (fp32 accumulate)
__device__ __forceinline__ float dot2(uint32_t w, uint32_t h, float acc) {
#if __has_builtin(__builtin_amdgcn_fdot2)
    union { uint32_t u; v2h v; } a, b;
    a.u = w; b.u = h;
    return __builtin_amdgcn_fdot2(a.v, b.v, acc, false);
#else
    union { uint32_t u; v2h v; } a, b;
    a.u = w; b.u = h;
    return acc + (float)a.v.x * (float)b.v.x + (float)a.v.y * (float)b.v.y;
#endif
}
// fast tanh: 1 - 2/(exp(2x)+1)
__device__ __forceinline__ float ftanh(float x) {
    const float t = __expf(2.f * x);
    return 1.f - 2.f * __builtin_amdgcn_rcpf(t + 1.f);
}

// 8 f16-pairs (16 k) of weights (k-major, stride) against packed h from LDS
#define DCHUNK8(WP, STRIDE, HQ, ACC)                                           \
    {                                                                          \
        uint4 hA = *(const uint4*)((HQ) + 0);                                  \
        uint4 hB = *(const uint4*)((HQ) + 4);                                  \
        ACC = dot2((WP)[(size_t)(0) * (STRIDE)], hA.x, ACC);                   \
        ACC = dot2((WP)[(size_t)(1) * (STRIDE)], hA.y, ACC);                   \
        ACC = dot2((WP)[(size_t)(2) * (STRIDE)], hA.z, ACC);                   \
        ACC = dot2((WP)[(size_t)(3) * (STRIDE)], hA.w, ACC);                   \
        ACC = dot2((WP)[(size_t)(4) * (STRIDE)], hB.x, ACC);                   \
        ACC = dot2((WP)[(size_t)(5) * (STRIDE)], hB.y, ACC);                   \
        ACC = dot2((WP)[(size_t)(6) * (STRIDE)], hB.z, ACC);                   \
        ACC = dot2((WP)[(size_t)(7) * (STRIDE)], hB.w, ACC);                   \
    }

// ---------------------------------------------------------------------------
// [R,C] -> [C,R] fp32 transpose (LDS tiled). Grid: (C/32, R/32), 256 threads.
// ---------------------------------------------------------------------------
__global__ __launch_bounds__(256) void transpose_kernel(
    const float* __restrict__ src, float* __restrict__ dst, int R, int C)
{
    __shared__ float t[32][33];
    const int bx = blockIdx.x * 32, by = blockIdx.y * 32;
    const int x = threadIdx.x & 31, y = threadIdx.x >> 5;   // y: 0..7
    #pragma unroll
    for (int dy = 0; dy < 32; dy += 8)
        t[y + dy][x] = src[(size_t)(by + y + dy) * C + bx + x];
    __syncthreads();
    #pragma unroll
    for (int dy = 0; dy < 32; dy += 8)
        dst[(size_t)(bx + y + dy) * R + by + x] = t[x][y + dy];
}

// ---------------------------------------------------------------------------
// Pack k-major fp32 [2P, J] into f16-pair uint32 [P, J]
// ---------------------------------------------------------------------------
__global__ __launch_bounds__(256) void pack_kernel(
    const float* __restrict__ in, uint32_t* __restrict__ out, int P, int J)
{
    const int idx = blockIdx.x * 256 + threadIdx.x;
    if (idx >= P * J) return;
    const int p = idx / J, j = idx - p * J;
    const ushort lo = f2h(in[(size_t)(2 * p) * J + j]);
    const ushort hi = f2h(in[(size_t)(2 * p + 1) * J + j]);
    out[idx] = ((uint32_t)hi << 16) | lo;
}

// ---------------------------------------------------------------------------
// fp32 -> bf16 convert (grid-stride)
// ---------------------------------------------------------------------------
__global__ __launch_bounds__(256) void cvt_bf16_kernel(
    const float* __restrict__ in, ushort* __restrict__ out, int n)
{
    const int stride = gridDim.x * 256;
    for (int i = blockIdx.x * 256 + threadIdx.x; i < n; i += stride)
        out[i] = f2b(in[i]);
}

// ---------------------------------------------------------------------------
// MFMA bf16 GEMM: C[m,n] = sum_k A[m,k]*B[n,k] + bias[n] (+ relpos).
// A,B bf16 row-major; 64x64 tile, 256 thr (4 waves), 16x16x32 MFMA.
// ASWAP: A row [s*B+b] while m = b*S+s.
// Frag layouts (guide-verified): A/B [idx=lane&15][k=quad*8+j]; C/D
// col=lane&15, row=quad*4+reg.
// ---------------------------------------------------------------------------
template<bool ASWAP, bool RELPOS>
__global__ __launch_bounds__(256) void mfma_gemm_kernel(
    const ushort* __restrict__ A16, const ushort* __restrict__ B16,
    const float* __restrict__ bias, const float* __restrict__ rp,
    float* __restrict__ C, int M, int N, int K)
{
    __shared__ ushort As[64][40];   // +8 pad: 2-way-max bank aliasing on b128
    __shared__ ushort Bs[64][40];
    const int tid = threadIdx.x;
    const int tile_m = blockIdx.x * 64, tile_n = blockIdx.y * 64;
    const int r = tid >> 2, c = (tid & 3) * 8;
    const int am = tile_m + r;
    const int ar = ASWAP ? ((am & (SDIM - 1)) * BDIM + (am >> 9)) : am;
    const int bn = tile_n + r;
    const int w = tid >> 6, lane = tid & 63;
    const int mi = lane & 15, quad = lane >> 4;
    f32x4 acc[4] = {};

    for (int k0 = 0; k0 < K; k0 += 32) {
        *(uint4*)&As[r][c] = *(const uint4*)(A16 + (size_t)ar * K + k0 + c);
        *(uint4*)&Bs[r][c] = *(const uint4*)(B16 + (size_t)bn * K + k0 + c);
        __syncthreads();
        const bf16x8 af = *(const bf16x8*)&As[w * 16 + mi][quad * 8];
        #pragma unroll
        for (int j = 0; j < 4; j++) {
            const bf16x8 bf = *(const bf16x8*)&Bs[j * 16 + mi][quad * 8];
            acc[j] = __builtin_amdgcn_mfma_f32_16x16x32_bf16(af, bf, acc[j], 0, 0, 0);
        }
        __syncthreads();
    }
    #pragma unroll
    for (int j = 0; j < 4; j++) {
        const int gn = tile_n + j * 16 + mi;
        const float bv = bias[gn];
        #pragma unroll
        for (int rr = 0; rr < 4; rr++) {
            const int gm = tile_m + w * 16 + quad * 4 + rr;
            float v = acc[j][rr] + bv;
            if (RELPOS) {
                const int sgm = gm & (SDIM - 1);
                v += rp[((gn >> 5) << 14) + (sgm << 5) + (gn & 31)];
            }
            C[(size_t)gm * N + gn] = v;
        }
    }
}

// ---------------------------------------------------------------------------
// Sequential PFN scan (round-5 verified f16/dot2 version; cumsoftmax without
// max-subtraction — |gates| <= ~12, exp is fp32-safe). One wg per batch elem.
// ---------------------------------------------------------------------------
__global__ __launch_bounds__(1024) void scan_kernel(
    const float* __restrict__ gx,       // [S,B,1280] precomputed x@Wi.T+bi
    const uint32_t* __restrict__ Wh2,   // [128,1280] f16 pairs over k
    const float* __restrict__ bh,       // [1280]
    const uint32_t* __restrict__ Wt2,   // [384,256] f16 pairs over k
    const float* __restrict__ bt,       // [256]
    ushort* __restrict__ h_ner,         // [S,B,256] bf16
    ushort* __restrict__ h_re)          // [S,B,256] bf16
{
    const int b = blockIdx.x;
    const int tid = threadIdx.x;
    __shared__ float cs[256], g[1280], ext[1024];
    __shared__ uint32_t hs_pk[128], cat_pk[384];
    __shared__ float rsum[16];
    if (tid < 256) cs[tid] = 0.f;
    if (tid < 128) hs_pk[tid] = 0u;
    __syncthreads();
    const int lane = tid & 63;
    const int ch = tid >> 8;            // cumsoftmax chunk 0..3
    const int wch = (tid >> 6) & 3;     // wave within chunk
    const int er = tid & 255;
    const int ep = tid >> 8;

    for (int t = 0; t < SDIM; t++) {
        const float* gxr = gx + (size_t)(t * BDIM + b) * 1280;
        // ---- gates = gx + bh + h @ Wh.T ----
        {
            float a1 = 0.f;
            const uint32_t* wc = Wh2 + tid;
            #pragma unroll 2
            for (int q = 0; q < 128; q += 8)
                DCHUNK8(wc + (size_t)q * 1280, 1280, hs_pk + q, a1);
            g[tid] = gxr[tid] + bh[tid] + a1;
        }
        {   // rows 1024..1279, k split 4 ways (32 pairs per part)
            float ae = 0.f;
            const uint32_t* wc = Wh2 + 1024 + er;
            const int qb = ep * 32;
            #pragma unroll 2
            for (int i = 0; i < 32; i += 8)
                DCHUNK8(wc + (size_t)(qb + i) * 1280, 1280, hs_pk + qb + i, ae);
            ext[ep * 256 + er] = ae;
        }
        __syncthreads();
        // ---- c = tanh(chunk0); cumsoftmax on chunks 1..4 (no max-sub) ----
        if (tid < 256) g[tid] = ftanh(g[tid]);
        float v;
        if (tid >= 768) {   // finish reduction for gate rows 1024..1279
            const int r_ = tid - 768;
            v = gxr[1024 + r_] + bh[1024 + r_]
              + ext[r_] + ext[256 + r_] + ext[512 + r_] + ext[768 + r_];
        } else {
            v = g[256 + tid];
        }
        const float e = __expf(v);
        float wsum = e;
        #pragma unroll
        for (int off = 32; off >= 1; off >>= 1) wsum += __shfl_xor(wsum, off, 64);
        if (lane == 0) rsum[ch * 4 + wch] = wsum;
        float cum = e;   // inclusive wave scan
        #pragma unroll
        for (int off = 1; off <= 32; off <<= 1) {
            float tsh = __shfl_up(cum, (unsigned)off, 64);
            if (lane >= off) cum += tsh;
        }
        __syncthreads();
        const float tot = rsum[ch * 4] + rsum[ch * 4 + 1] + rsum[ch * 4 + 2] + rsum[ch * 4 + 3];
        float prev = 0.f;
        if (wch > 0) prev += rsum[ch * 4];
        if (wch > 1) prev += rsum[ch * 4 + 1];
        if (wch > 2) prev += rsum[ch * 4 + 2];
        float r = (cum + prev) * __builtin_amdgcn_rcpf(tot);
        if (ch == 0 || ch == 2) r = 1.f - r;   // eg_* = 1 - cumsoftmax
        g[256 + tid] = r;
        __syncthreads();
        // ---- combine gates -> c_re, c_ner, share; emit h_ner/h_re (bf16) ----
        if (tid < 256) {
            const float c = g[tid];
            const float egi = g[256 + tid], rgi = g[512 + tid];
            const float egc = g[768 + tid], rgc = g[1024 + tid];
            const float cin = cs[tid];
            const float ovc = rgc * egc, upc = rgc - ovc, dnc = egc - ovc;
            const float ovi = rgi * egi, upi = rgi - ovi, dni = egi - ovi;
            const float share = ovi * cin + ovc * c;
            const float cre = upi * cin + upc * c + share;
            const float cner = dni * cin + dnc * c + share;
            ((_Float16*)cat_pk)[tid]       = (_Float16)cre;
            ((_Float16*)cat_pk)[256 + tid] = (_Float16)cner;
            ((_Float16*)cat_pk)[512 + tid] = (_Float16)share;
            const size_t ob = (size_t)(t * BDIM + b) * 256 + tid;
            h_re[ob] = f2b(ftanh(cre));
            h_ner[ob] = f2b(ftanh(cner));
        }
        __syncthreads();
        // ---- c_out = cat @ Wt.T + bt (4 k-partials of 96 pairs per output) ----
        {
            float s = 0.f;
            const uint32_t* wc = Wt2 + er;
            const int qb = ep * 96;
            #pragma unroll 2
            for (int i = 0; i < 96; i += 8)
                DCHUNK8(wc + (size_t)(qb + i) * 256, 256, cat_pk + qb + i, s);
            g[ep * 256 + er] = s;
        }
        __syncthreads();
        if (tid < 256) {
            const float co = g[tid] + g[256 + tid] + g[512 + tid] + g[768 + tid] + bt[tid];
            cs[tid] = co;
            ((_Float16*)hs_pk)[tid] = (_Float16)ftanh(co);
        }
        __syncthreads();
    }
}

// ---------------------------------------------------------------------------
// Attention for one (b, head): scores = q·(k+relpos) (relpos pre-folded into
// kk_ws), softmax, PV. Output stored bf16 for the MFMA out-projection.
// ---------------------------------------------------------------------------
__global__ __launch_bounds__(512) void attn_kernel(
    const float* __restrict__ q_ws, const float* __restrict__ kk_ws,
    const float* __restrict__ v_ws, ushort* __restrict__ o16)
{
    __shared__ float sc[8 * 516];   // 8 q-rows x 512 probs, stride 516 (bank pad)
    __shared__ float ps[8 * 256];   // PV partials per wave
    __shared__ float sinv[8];
    const int bn = blockIdx.x;
    const int b = bn >> 3, n = bn & 7;
    const int tid = threadIdx.x;
    const int w = tid >> 6, lane = tid & 63;
    const int ki = w * 64 + lane;
    float kv[32];
    {
        const float4* kp = (const float4*)(kk_ws + (size_t)(b * 512 + ki) * 256 + n * 32);
        #pragma unroll
        for (int d4 = 0; d4 < 8; d4++) {
            float4 x = kp[d4];
            kv[4 * d4] = x.x; kv[4 * d4 + 1] = x.y; kv[4 * d4 + 2] = x.z; kv[4 * d4 + 3] = x.w;
        }
    }
    const int rr = lane >> 3, dq = lane & 7;

    for (int q0 = 0; q0 < 512; q0 += 8) {
        const float* qbase = q_ws + (size_t)(b * 512 + q0) * 256 + n * 32;
        #pragma unroll 1
        for (int r = 0; r < 8; r++) {
            const float* qr = qbase + r * 256;   // wave-uniform address
            float s = 0.f;
            #pragma unroll
            for (int d = 0; d < 32; d++) s += qr[d] * kv[d];
            sc[r * 516 + ki] = s;
        }
        __syncthreads();
        // softmax of row w by wave w
        {
            float* row = sc + w * 516;
            float4 a = ((const float4*)row)[lane];
            float4 c4 = ((const float4*)row)[lane + 64];
            float mx = fmaxf(fmaxf(fmaxf(a.x, a.y), fmaxf(a.z, a.w)),
                             fmaxf(fmaxf(c4.x, c4.y), fmaxf(c4.z, c4.w)));
            #pragma unroll
            for (int off = 32; off >= 1; off >>= 1) mx = fmaxf(mx, __shfl_xor(mx, off, 64));
            a.x = __expf(a.x - mx); a.y = __expf(a.y - mx);
            a.z = __expf(a.z - mx); a.w = __expf(a.w - mx);
            c4.x = __expf(c4.x - mx); c4.y = __expf(c4.y - mx);
            c4.z = __expf(c4.z - mx); c4.w = __expf(c4.w - mx);
            float sm = a.x + a.y + a.z + a.w + c4.x + c4.y + c4.z + c4.w;
            #pragma unroll
            for (int off = 32; off >= 1; off >>= 1) sm += __shfl_xor(sm, off, 64);
            ((float4*)row)[lane] = a;
            ((float4*)row)[lane + 64] = c4;
            if (lane == 0) sinv[w] = 1.f / sm;
        }
        __syncthreads();
        // PV: wave w covers ki in [w*64, w*64+64); lane -> (row rr, 4 dims dq*4)
        {
            float4 acc = {0.f, 0.f, 0.f, 0.f};
            const float* erow = sc + rr * 516 + w * 64;
            const float* vbase = v_ws + (size_t)(b * 512 + w * 64) * 256 + n * 32 + dq * 4;
            #pragma unroll 8
            for (int j = 0; j < 64; j++) {
                const float e = erow[j];
                float4 vv = *(const float4*)(vbase + (size_t)j * 256);
                acc.x += e * vv.x; acc.y += e * vv.y; acc.z += e * vv.z; acc.w += e * vv.w;
            }
            ((float4*)ps)[tid] = acc;
        }
        __syncthreads();
        if (tid < 256) {
            const int r2 = tid >> 5, d = tid & 31;
            float s = 0.f;
            #pragma unroll
            for (int ww = 0; ww < 8; ww++) s += ps[ww * 256 + r2 * 32 + d];
            o16[(size_t)(b * 512 + q0 + r2) * 256 + n * 32 + d] = f2b(s * sinv[r2]);
        }
        __syncthreads();
    }
}

// ---------------------------------------------------------------------------
// y = LN(hb + proj) -> fp32 output in [S,B,H] order (residual hb is bf16)
// ---------------------------------------------------------------------------
__global__ __launch_bounds__(256) void ln_kernel(
    const float* __restrict__ proj, const ushort* __restrict__ hsrc,
    const float* __restrict__ lng, const float* __restrict__ lnb,
    float* __restrict__ outp)
{
    const int m = blockIdx.x;           // b*512 + s
    const int j = threadIdx.x;
    const int b = m >> 9, s = m & 511;
    const size_t oidx = (size_t)(s * 32 + b) * 256 + j;
    const float y = proj[(size_t)m * 256 + j] + b2f(hsrc[oidx]);
    float sum = y, sq = y * y;
    #pragma unroll
    for (int off = 32; off >= 1; off >>= 1) {
        sum += __shfl_xor(sum, off, 64);
        sq += __shfl_xor(sq, off, 64);
    }
    __shared__ float r1[4], r2[4];
    const int wv = j >> 6;
    if ((j & 63) == 0) { r1[wv] = sum; r2[wv] = sq; }
    __syncthreads();
    const float ts = r1[0] + r1[1] + r1[2] + r1[3];
    const float tq = r2[0] + r2[1] + r2[2] + r2[3];
    const float mean = ts * (1.f / 256.f);
    const float var = tq * (1.f / 256.f) - mean * mean;
    const float o = (y - mean) * rsqrtf(var + 1e-5f) * lng[j] + lnb[j];
    outp[oidx] = o;
}

extern "C" void kernel_launch(void* const* d_in, const int* in_sizes, int n_in,
                              void* d_out, int out_size, void* d_ws, size_t ws_size,
                              hipStream_t stream) {
    (void)in_sizes; (void)n_in; (void)out_size; (void)ws_size;
    const float* x   = (const float*)d_in[0];
    const float* Wi  = (const float*)d_in[1];
    const float* bi  = (const float*)d_in[2];
    const float* Wh  = (const float*)d_in[3];
    const float* bh  = (const float*)d_in[4];
    const float* Wt  = (const float*)d_in[5];
    const float* bt  = (const float*)d_in[6];
    const float* Wq  = (const float*)d_in[7];
    const float* bq  = (const float*)d_in[8];
    const float* Wk  = (const float*)d_in[9];
    const float* bk  = (const float*)d_in[10];
    const float* Wv  = (const float*)d_in[11];
    const float* bv  = (const float*)d_in[12];
    const float* Wo  = (const float*)d_in[13];
    const float* bo  = (const float*)d_in[14];
    const float* rp  = (const float*)d_in[15];
    const float* lng = (const float*)d_in[16];
    const float* lnb = (const float*)d_in[17];
    float* outp = (float*)d_out;

    float* ws = (float*)d_ws;
    // pool [0, 20971520): gx fp32 [16384,1280] during pre-scan/scan; attention
    // scratch afterwards (q/kk/v fp32, pj fp32, o16 bf16).
    float* gx    = ws;
    float* q_ws  = ws;
    float* kk_ws = ws + 4194304;
    float* v_ws  = ws + 8388608;
    float* pj_ws = ws + 12582912;
    ushort* o16  = (ushort*)(ws + 16777216);     // [16384,256] bf16
    ushort* hner16 = (ushort*)(ws + 20971520);   // [S,B,256] bf16
    ushort* hre16  = (ushort*)(ws + 23068672);
    uint32_t* Wh2 = (uint32_t*)(ws + 25165824);  // [128,1280] f16 pairs
    uint32_t* Wt2 = (uint32_t*)(ws + 25329664);  // [384,256] f16 pairs
    ushort* Wq16 = (ushort*)(ws + 25427968);     // [3,256,256] bf16
    ushort* Wk16 = (ushort*)(ws + 25526272);
    ushort* Wv16 = (ushort*)(ws + 25624576);
    ushort* Wo16 = (ushort*)(ws + 25722880);     // ends 25821184 (<= r5 footprint)

    // d_out doubles as pre-scan scratch (validated only after final ln writes):
    ushort* x16  = (ushort*)outp;                // [16384,768] bf16 (6291456 f)
    ushort* Wi16 = (ushort*)(outp + 6291456);    // [1280,768] bf16 (491520 f)
    float* WhT   = outp + 6782976;               // [256,1280] fp32
    float* WtT   = outp + 7110656;               // [768,256] fp32, ends 7307264

    // 0) weight prep: scan f16 packs + bf16 GEMM operands
    transpose_kernel<<<dim3(8, 40), 256, 0, stream>>>(Wh, WhT, 1280, 256);
    transpose_kernel<<<dim3(24, 8), 256, 0, stream>>>(Wt, WtT, 256, 768);
    pack_kernel<<<dim3(640), 256, 0, stream>>>(WhT, Wh2, 128, 1280);
    pack_kernel<<<dim3(384), 256, 0, stream>>>(WtT, Wt2, 384, 256);
    cvt_bf16_kernel<<<dim3(4096), 256, 0, stream>>>(x, x16, 12582912);
    cvt_bf16_kernel<<<dim3(1024), 256, 0, stream>>>(Wi, Wi16, 983040);
    cvt_bf16_kernel<<<dim3(256), 256, 0, stream>>>(Wq, Wq16, 196608);
    cvt_bf16_kernel<<<dim3(256), 256, 0, stream>>>(Wk, Wk16, 196608);
    cvt_bf16_kernel<<<dim3(256), 256, 0, stream>>>(Wv, Wv16, 196608);
    cvt_bf16_kernel<<<dim3(256), 256, 0, stream>>>(Wo, Wo16, 196608);

    // 1) gates_x = x @ Wi.T + bi   [16384,1280]  (MFMA)
    mfma_gemm_kernel<false, false><<<dim3(256, 20), 256, 0, stream>>>(
        x16, Wi16, bi, nullptr, gx, 16384, 1280, 768);

    // 2) sequential scan (one block per batch element)
    scan_kernel<<<dim3(32), dim3(1024), 0, stream>>>(gx, Wh2, bh, Wt2, bt, hner16, hre16);

    // 3) three attentions: (h_ner,0), (h_re,1), (h_re,2)
    for (int i = 0; i < 3; i++) {
        const ushort* src16 = (i == 0) ? hner16 : hre16;
        mfma_gemm_kernel<true, false><<<dim3(256, 4), 256, 0, stream>>>(
            src16, Wq16 + (size_t)i * 65536, bq + i * 256, nullptr, q_ws, 16384, 256, 256);
        mfma_gemm_kernel<true, true><<<dim3(256, 4), 256, 0, stream>>>(
            src16, Wk16 + (size_t)i * 65536, bk + i * 256, rp + (size_t)i * 131072, kk_ws, 16384, 256, 256);
        mfma_gemm_kernel<true, false><<<dim3(256, 4), 256, 0, stream>>>(
            src16, Wv16 + (size_t)i * 65536, bv + i * 256, nullptr, v_ws, 16384, 256, 256);
        attn_kernel<<<dim3(256), dim3(512), 0, stream>>>(q_ws, kk_ws, v_ws, o16);
        mfma_gemm_kernel<false, false><<<dim3(256, 4), 256, 0, stream>>>(
            o16, Wo16 + (size_t)i * 65536, bo + i * 256, nullptr, pj_ws, 16384, 256, 256);
        ln_kernel<<<dim3(16384), dim3(256), 0, stream>>>(
            pj_ws, src16, lng, lnb, outp + (size_t)i * 4194304);
    }
}